// Round 6
// baseline (322.339 us; speedup 1.0000x reference)
//
#include <hip/hip_runtime.h>
#include <cstdint>
#include <cstddef>

#define N_NODES   50000
#define N_EDGES   600000
#define DIM       128
#define NLAYERS   4
#define N_GRAPHS  64
#define N_PATIENTS 50
#define ROWS      32

typedef __attribute__((ext_vector_type(8))) __bf16        bf16x8;
typedef __attribute__((ext_vector_type(4))) float         f32x4;
typedef __attribute__((ext_vector_type(4))) unsigned int  u32x4;
typedef __attribute__((ext_vector_type(8))) unsigned short u16x8;

__device__ inline unsigned short f2bf(float f) {
    unsigned u = __builtin_bit_cast(unsigned, f);
    u += 0x7FFFu + ((u >> 16) & 1u);   // round-to-nearest-even
    return (unsigned short)(u >> 16);
}

__device__ inline float bf2f(unsigned short s) {
    return __builtin_bit_cast(float, (unsigned)s << 16);
}

__device__ inline f32x4 lo4(u16x8 u) {
    f32x4 r;
    r[0] = bf2f(u[0]); r[1] = bf2f(u[1]); r[2] = bf2f(u[2]); r[3] = bf2f(u[3]);
    return r;
}
__device__ inline f32x4 hi4(u16x8 u) {
    f32x4 r;
    r[0] = bf2f(u[4]); r[1] = bf2f(u[5]); r[2] = bf2f(u[6]); r[3] = bf2f(u[7]);
    return r;
}

// ---------------- CSR build ----------------

__global__ void k_count(const int* __restrict__ ei, int* __restrict__ counts) {
    int e = blockIdx.x * 256 + threadIdx.x;
    if (e < N_EDGES) atomicAdd(&counts[ei[N_EDGES + e]], 1);
}

__global__ void k_scan_a(const int* __restrict__ counts, int* __restrict__ incl,
                         int* __restrict__ bsums, int n) {
    __shared__ int s[256];
    int i = blockIdx.x * 256 + threadIdx.x;
    int v = (i < n) ? counts[i] : 0;
    s[threadIdx.x] = v;
    __syncthreads();
    for (int off = 1; off < 256; off <<= 1) {
        int t = (threadIdx.x >= off) ? s[threadIdx.x - off] : 0;
        __syncthreads();
        s[threadIdx.x] += t;
        __syncthreads();
    }
    if (i < n) incl[i] = s[threadIdx.x];
    if (threadIdx.x == 255) bsums[blockIdx.x] = s[255];
}

__global__ void k_scan_b(int* __restrict__ bsums, int nb) {
    __shared__ int s[256];
    int t = threadIdx.x;
    int v = (t < nb) ? bsums[t] : 0;
    s[t] = v;
    __syncthreads();
    for (int off = 1; off < 256; off <<= 1) {
        int u = (t >= off) ? s[t - off] : 0;
        __syncthreads();
        s[t] += u;
        __syncthreads();
    }
    if (t < nb) bsums[t] = s[t];
}

__global__ void k_scan_c(const int* __restrict__ counts, const int* __restrict__ incl,
                         const int* __restrict__ bsums, int* __restrict__ row_ptr,
                         int* __restrict__ cursor, int n) {
    int i = blockIdx.x * 256 + threadIdx.x;
    if (i < n) {
        int off = blockIdx.x ? bsums[blockIdx.x - 1] : 0;
        int ex  = incl[i] - counts[i] + off;
        row_ptr[i] = ex;
        cursor[i]  = ex;
        if (i == n - 1) row_ptr[n] = incl[i] + off;
    }
}

__global__ void k_fill(const int* __restrict__ ei, int* __restrict__ cursor,
                       int* __restrict__ esorted) {
    int e = blockIdx.x * 256 + threadIdx.x;
    if (e < N_EDGES) {
        int d   = ei[N_EDGES + e];
        int pos = atomicAdd(&cursor[d], 1);
        esorted[pos] = ei[e];
    }
}

// ---------------- x -> bf16 copy ----------------

__global__ void k_prep(const float* __restrict__ x, unsigned short* __restrict__ xb) {
    int idx = blockIdx.x * 256 + threadIdx.x;        // one u16x8 per thread
    if (idx < N_NODES * DIM / 8) {
        f32x4 v0 = *(const f32x4*)(x + (size_t)idx * 8);
        f32x4 v1 = *(const f32x4*)(x + (size_t)idx * 8 + 4);
        u16x8 o = { f2bf(v0[0]), f2bf(v0[1]), f2bf(v0[2]), f2bf(v0[3]),
                    f2bf(v1[0]), f2bf(v1[1]), f2bf(v1[2]), f2bf(v1[3]) };
        *(u16x8*)(xb + (size_t)idx * 8) = o;
    }
}

// ---------------- W precombine: Wt[l][c][k] = bf16(Wcat[k][c]) ----------------

__global__ void k_wt(const float* __restrict__ Wroot, const float* __restrict__ Wrel,
                     unsigned short* __restrict__ Wt) {
    int idx = blockIdx.x * 256 + threadIdx.x;   // l*32768 + c*256 + k
    if (idx < NLAYERS * DIM * 256) {
        int l = idx >> 15;
        int c = (idx >> 8) & 127;
        int k = idx & 255;
        float v = (k < 128) ? Wroot[l * 16384 + k * 128 + c]
                            : Wrel[l * 16384 + (k - 128) * 128 + c];
        Wt[idx] = f2bf(v);
    }
}

// ---------------- fused layer (512 threads, 32 rows, bf16 carry) ----------------

__global__ __launch_bounds__(512, 8) void k_layer(
    const unsigned short* __restrict__ xb,        // bf16 x (input)
    unsigned short* __restrict__ xbnext,          // bf16 x (output)
    const int* __restrict__ row_ptr, const int* __restrict__ esrc,
    const unsigned short* __restrict__ Wt,        // [128][256] bf16, linear
    const float* __restrict__ bconv, const float* __restrict__ gamma,
    const float* __restrict__ beta,
    const float* __restrict__ bW, const float* __restrict__ bb,
    float* __restrict__ boundary, int last)
{
    __shared__ __align__(16) unsigned short x2s[ROWS * 256];   // 16 KB, XOR-swizzled
    __shared__ float rsum[ROWS][4], rsq[ROWS][4], rbl[ROWS][4];
    const int tid     = threadIdx.x;
    const int rowbase = blockIdx.x * ROWS;
    const int lane = tid & 63, w = tid >> 6;

    // phase 1a: x row (bf16) -> LDS cols [0,128). 16-lane group per row.
    {
        int grp = tid >> 4, li = tid & 15;
        int grow = rowbase + grp;
        int rx = (grp & 7) << 4;
        u16x8 v = { 0, 0, 0, 0, 0, 0, 0, 0 };
        if (grow < N_NODES) v = *(const u16x8*)(xb + (size_t)grow * DIM + li * 8);
        int byteoff = (grp * 512 + li * 16) ^ rx;
        *(u16x8*)((char*)x2s + byteoff) = v;
    }

    // phase 1b: CSR neighbor-sum -> LDS cols [128,256).
    // ONE ROW PER WAVE: 64 lanes = 4 edges (eo) x 16 slices (li); wave-uniform
    // bounds (no divergence). 16-edge index prefetch, cross-row pipelined.
    {
        int eo = lane >> 4, li = lane & 15;
        int rbase = w * 4;
        int bg[4], dg[4];
        #pragma unroll
        for (int r = 0; r < 4; r++) {
            int grow = rowbase + rbase + r;
            int b = 0, n = 0;
            if (grow < N_NODES) { b = row_ptr[grow]; n = row_ptr[grow + 1] - b; }
            bg[r] = b; dg[r] = n;
        }
        const u16x8 z = { 0, 0, 0, 0, 0, 0, 0, 0 };
        int i0, i1, i2, i3;
        {
            int b = bg[0], n = dg[0];
            i0 = (eo      < n) ? esrc[b + eo]      : -1;
            i1 = (eo + 4  < n) ? esrc[b + eo + 4]  : -1;
            i2 = (eo + 8  < n) ? esrc[b + eo + 8]  : -1;
            i3 = (eo + 12 < n) ? esrc[b + eo + 12] : -1;
        }
        #pragma unroll
        for (int r = 0; r < 4; r++) {
            // issue next row's index loads first (overlaps current row's loads)
            int n0 = -1, n1 = -1, n2 = -1, n3 = -1;
            if (r < 3) {
                int b = bg[r + 1], n = dg[r + 1];
                n0 = (eo      < n) ? esrc[b + eo]      : -1;
                n1 = (eo + 4  < n) ? esrc[b + eo + 4]  : -1;
                n2 = (eo + 8  < n) ? esrc[b + eo + 8]  : -1;
                n3 = (eo + 12 < n) ? esrc[b + eo + 12] : -1;
            }
            // 16 row-loads in flight (4 per lane)
            u16x8 v0 = z, v1 = z, v2 = z, v3 = z;
            if (i0 >= 0) v0 = *(const u16x8*)(xb + (size_t)i0 * DIM + li * 8);
            if (i1 >= 0) v1 = *(const u16x8*)(xb + (size_t)i1 * DIM + li * 8);
            if (i2 >= 0) v2 = *(const u16x8*)(xb + (size_t)i2 * DIM + li * 8);
            if (i3 >= 0) v3 = *(const u16x8*)(xb + (size_t)i3 * DIM + li * 8);
            f32x4 a0 = (lo4(v0) + lo4(v1)) + (lo4(v2) + lo4(v3));
            f32x4 a1 = (hi4(v0) + hi4(v1)) + (hi4(v2) + hi4(v3));
            // rare tail: degree > 16
            int n = dg[r], b = bg[r];
            for (int e = 16; e < n; e += 4) {
                int idx = (e + eo < n) ? esrc[b + e + eo] : -1;
                u16x8 v = z;
                if (idx >= 0) v = *(const u16x8*)(xb + (size_t)idx * DIM + li * 8);
                a0 += lo4(v); a1 += hi4(v);
            }
            // combine the 4 eo-groups: lanes l, l+16, l+32, l+48 hold same slice
            #pragma unroll
            for (int k = 0; k < 4; k++) {
                a0[k] += __shfl_xor(a0[k], 16);
                a0[k] += __shfl_xor(a0[k], 32);
                a1[k] += __shfl_xor(a1[k], 16);
                a1[k] += __shfl_xor(a1[k], 32);
            }
            if (eo == 0) {
                int row = rbase + r;
                u16x8 o = { f2bf(a0[0]), f2bf(a0[1]), f2bf(a0[2]), f2bf(a0[3]),
                            f2bf(a1[0]), f2bf(a1[1]), f2bf(a1[2]), f2bf(a1[3]) };
                int byteoff = (row * 512 + 256 + li * 16) ^ ((row & 7) << 4);
                *(u16x8*)((char*)x2s + byteoff) = o;
            }
            i0 = n0; i1 = n1; i2 = n2; i3 = n3;
        }
    }
    __syncthreads();

    // phase 2: [32x256] @ [256x128]. Wave w: rowtile rt = w>>2, colquarter cq = w&3.
    int colb = lane & 15, kg = lane >> 4;
    int rt = w >> 2, cq = w & 3;

    u32x4 araw[8];
    {
        int row  = rt * 16 + colb;
        int base = row * 512 + kg * 16;
        int rx   = (row & 7) << 4;
        #pragma unroll
        for (int ks = 0; ks < 8; ks++) {
            int byteoff = (base + ks * 64) ^ rx;
            araw[ks] = *(const u32x4*)((const char*)x2s + byteoff);
        }
    }

    f32x4 acc[2];
    acc[0] = 0.0f; acc[1] = 0.0f;

    #pragma unroll
    for (int cb = 0; cb < 2; cb++) {
        const unsigned short* wp = Wt + ((cq * 32 + cb * 16 + colb) * 256 + kg * 8);
        #pragma unroll
        for (int ks = 0; ks < 8; ks++) {
            u32x4 braw = *(const u32x4*)(wp + ks * 32);
            acc[cb] = __builtin_amdgcn_mfma_f32_16x16x32_bf16(
                __builtin_bit_cast(bf16x8, araw[ks]),
                __builtin_bit_cast(bf16x8, braw), acc[cb], 0, 0, 0);
        }
    }

    // epilogue part 1: per-row partial sums (32 cols per wave) -> LDS slots
    float hv[4][2];
    #pragma unroll
    for (int j = 0; j < 4; j++) {
        float ps = 0.f, pq = 0.f;
        #pragma unroll
        for (int cb = 0; cb < 2; cb++) {
            int col = cq * 32 + cb * 16 + colb;
            float h = acc[cb][j] + bconv[col];
            hv[j][cb] = h; ps += h; pq += h * h;
        }
        #pragma unroll
        for (int m = 1; m < 16; m <<= 1) {
            ps += __shfl_xor(ps, m);
            pq += __shfl_xor(pq, m);
        }
        if (colb == 0) {
            int lr = rt * 16 + kg * 4 + j;
            rsum[lr][cq] = ps;
            rsq[lr][cq]  = pq;
        }
    }
    __syncthreads();

    // epilogue part 2: LN, ELU, residual (from LDS bf16), bf16 store, boundary
    #pragma unroll
    for (int j = 0; j < 4; j++) {
        int lr   = rt * 16 + kg * 4 + j;
        int grow = rowbase + lr;
        float sum = rsum[lr][0] + rsum[lr][1] + rsum[lr][2] + rsum[lr][3];
        float sq  = rsq[lr][0] + rsq[lr][1] + rsq[lr][2] + rsq[lr][3];
        float mean = sum * (1.f / 128.f);
        float var  = sq * (1.f / 128.f) - mean * mean;
        float rs   = rsqrtf(var + 1e-5f);
        float bl = 0.f;
        if (grow < N_NODES) {
            int rx = (lr & 7) << 4;
            #pragma unroll
            for (int cb = 0; cb < 2; cb++) {
                int col  = cq * 32 + cb * 16 + colb;
                float hn = (hv[j][cb] - mean) * rs * gamma[col] + beta[col];
                hn = hn > 0.f ? hn : (expf(hn) - 1.f);
                int xoff = (lr * 512 + col * 2) ^ rx;
                float xi = bf2f(*(const unsigned short*)((const char*)x2s + xoff));
                float xo = hn + xi;
                xbnext[(size_t)grow * DIM + col] = f2bf(xo);
                bl += xo * bW[col];
            }
        }
        if (last) {
            #pragma unroll
            for (int m = 1; m < 16; m <<= 1) bl += __shfl_xor(bl, m);
            if (colb == 0) rbl[lr][cq] = bl;
        }
    }
    if (last) {
        __syncthreads();
        if (tid < ROWS && rowbase + tid < N_NODES)
            boundary[rowbase + tid] = rbl[tid][0] + rbl[tid][1] + rbl[tid][2] + rbl[tid][3] + bb[0];
    }
}

// ---------------- mean-pool per graph (batch is sorted, x in bf16) ----------------

__global__ void k_pool(const unsigned short* __restrict__ xb, const int* __restrict__ batch,
                       float* __restrict__ pooled, int* __restrict__ gcount) {
    __shared__ float2 s[64][4];
    int g = blockIdx.x >> 4, q = blockIdx.x & 15;
    int lo = 0, hi = N_NODES;
    while (lo < hi) { int m = (lo + hi) >> 1; if (batch[m] < g) lo = m + 1; else hi = m; }
    int s0 = lo;
    lo = 0; hi = N_NODES;
    while (lo < hi) { int m = (lo + hi) >> 1; if (batch[m] < g + 1) lo = m + 1; else hi = m; }
    int e0  = lo;
    int len = e0 - s0;
    int r0 = s0 + (int)((long long)len * q / 16);
    int r1 = s0 + (int)((long long)len * (q + 1) / 16);
    int cp = threadIdx.x & 63, rp = threadIdx.x >> 6;     // col pair, 4-way row split
    float ax = 0.f, ay = 0.f;
    for (int r = r0 + rp; r < r1; r += 4) {
        unsigned u = *(const unsigned*)(xb + (size_t)r * DIM + cp * 2);
        ax += bf2f((unsigned short)(u & 0xFFFF));
        ay += bf2f((unsigned short)(u >> 16));
    }
    s[cp][rp] = make_float2(ax, ay);
    __syncthreads();
    if (rp == 0) {
        float2 v1 = s[cp][1], v2 = s[cp][2], v3 = s[cp][3];
        ax += v1.x + v2.x + v3.x;
        ay += v1.y + v2.y + v3.y;
        atomicAdd(&pooled[g * DIM + cp * 2], ax);
        atomicAdd(&pooled[g * DIM + cp * 2 + 1], ay);
    }
    if (q == 0 && threadIdx.x == 0) gcount[g] = len;
}

// ---------------- domain head: thread-per-output, no LDS ----------------

__global__ __launch_bounds__(256) void k_dom1(
    const float* __restrict__ pooled, const int* __restrict__ gcount,
    const float* __restrict__ W1, const float* __restrict__ b1,
    float* __restrict__ h1g)
{
    int o = blockIdx.x * 256 + threadIdx.x;       // 64*64 outputs
    if (o < 64 * 64) {
        int i = o >> 6, j = o & 63;
        float cnt = (float)gcount[i];
        float rc = 1.f / (cnt < 1.f ? 1.f : cnt);
        float s = b1[j];
        #pragma unroll 8
        for (int k = 0; k < 128; k++) s += pooled[i * 128 + k] * rc * W1[k * 64 + j];
        h1g[o] = s > 0.f ? s : (expf(s) - 1.f);
    }
}

__global__ __launch_bounds__(256) void k_dom2(
    const float* __restrict__ h1g,
    const float* __restrict__ W2, const float* __restrict__ b2,
    float* __restrict__ out)
{
    int o = blockIdx.x * 256 + threadIdx.x;       // 64*50 outputs
    if (o < 64 * N_PATIENTS) {
        int i = o / N_PATIENTS, p = o - i * N_PATIENTS;
        float s = b2[p];
        #pragma unroll 8
        for (int k = 0; k < 64; k++) s += h1g[i * 64 + k] * W2[k * N_PATIENTS + p];
        out[o] = s;
    }
}

// ---------------- launch ----------------

extern "C" void kernel_launch(void* const* d_in, const int* in_sizes, int n_in,
                              void* d_out, int out_size, void* d_ws, size_t ws_size,
                              hipStream_t stream) {
    const float* x     = (const float*)d_in[0];
    const int*   ei    = (const int*)d_in[1];
    const int*   batch = (const int*)d_in[2];
    const float* Wroot = (const float*)d_in[3];
    const float* Wrel  = (const float*)d_in[4];
    const float* bconv = (const float*)d_in[5];
    const float* gamma = (const float*)d_in[6];
    const float* beta  = (const float*)d_in[7];
    const float* bW    = (const float*)d_in[8];
    const float* bb    = (const float*)d_in[9];
    const float* W1    = (const float*)d_in[10];
    const float* b1    = (const float*)d_in[11];
    const float* W2    = (const float*)d_in[12];
    const float* b2    = (const float*)d_in[13];
    float* out = (float*)d_out;

    char* ws = (char*)d_ws;
    size_t off = 0;
    auto alloc = [&](size_t bytes) -> char* {
        char* p = ws + off;
        off += (bytes + 255) & ~(size_t)255;
        return p;
    };
    unsigned short* xbA     = (unsigned short*)alloc((size_t)N_NODES * DIM * 2);
    unsigned short* xbB     = (unsigned short*)alloc((size_t)N_NODES * DIM * 2);
    unsigned short* Wt      = (unsigned short*)alloc((size_t)NLAYERS * DIM * 256 * 2);
    int*            counts  = (int*)alloc((size_t)N_NODES * 4);
    int*            incl    = (int*)alloc((size_t)N_NODES * 4);
    int*            row_ptr = (int*)alloc((size_t)(N_NODES + 1) * 4);
    int*            cursor  = (int*)alloc((size_t)N_NODES * 4);
    int*            esorted = (int*)alloc((size_t)N_EDGES * 4);
    int*            bsums   = (int*)alloc(256 * 4);
    float*          pooled  = (float*)alloc((size_t)N_GRAPHS * DIM * 4);
    int*            gcount  = (int*)alloc((size_t)N_GRAPHS * 4);
    float*          h1g     = (float*)alloc((size_t)64 * 64 * 4);
    (void)ws_size; (void)in_sizes; (void)n_in; (void)out_size;

    hipMemsetAsync(counts, 0, (size_t)N_NODES * 4, stream);
    hipMemsetAsync(pooled, 0, (size_t)N_GRAPHS * DIM * 4, stream);

    k_wt<<<(NLAYERS * DIM * 256 + 255) / 256, 256, 0, stream>>>(Wroot, Wrel, Wt);
    k_prep<<<(N_NODES * DIM / 8 + 255) / 256, 256, 0, stream>>>(x, xbA);
    k_count<<<(N_EDGES + 255) / 256, 256, 0, stream>>>(ei, counts);
    int nb = (N_NODES + 255) / 256;
    k_scan_a<<<nb, 256, 0, stream>>>(counts, incl, bsums, N_NODES);
    k_scan_b<<<1, 256, 0, stream>>>(bsums, nb);
    k_scan_c<<<nb, 256, 0, stream>>>(counts, incl, bsums, row_ptr, cursor, N_NODES);
    k_fill<<<(N_EDGES + 255) / 256, 256, 0, stream>>>(ei, cursor, esorted);

    int lgrid = (N_NODES + ROWS - 1) / ROWS;
    const unsigned short* xbi = xbA;
    unsigned short* xbo = xbB;
    for (int l = 0; l < NLAYERS; l++) {
        int last = (l == NLAYERS - 1);
        k_layer<<<lgrid, 512, 0, stream>>>(xbi, xbo,
                                           row_ptr, esorted, Wt + (size_t)l * DIM * 256,
                                           bconv + l * DIM, gamma + l * DIM, beta + l * DIM,
                                           bW, bb, out, last);
        const unsigned short* t = xbi; xbi = xbo; xbo = (unsigned short*)t;
    }
    k_pool<<<N_GRAPHS * 16, 256, 0, stream>>>(xbi, batch, pooled, gcount);
    k_dom1<<<16, 256, 0, stream>>>(pooled, gcount, W1, b1, h1g);
    k_dom2<<<(64 * N_PATIENTS + 255) / 256, 256, 0, stream>>>(h1g, W2, b2, out + N_NODES);
}